// Round 7
// baseline (227.876 us; speedup 1.0000x reference)
//
#include <hip/hip_runtime.h>
#include <hip/hip_bf16.h>
#include <math.h>

// NoisyTopkRouter round 13: amplify the r12 win (address-stream efficiency).
// r12 post-mortem: K-phase rotation was the FIRST change in 6 rounds to move
// the number (router 81.5 -> <77.2, out of top-5; total -7.8us). Confirms
// service-rate theory; residual derate ~5x vs the fills' 6.9 TB/s streams.
// All 512 blocks are co-resident (2/CU) -> a stage spans ~4.5us; only
// aggregate address-stream efficiency + total bytes matter.
// This round:
//  1. KSTAGE 64->128 (512B per row-visit): 2x bytes per DRAM page activate
//     (sequential streams get ~8x more data/activate than our 256B visits).
//     8 stages, half the barriers.
//  2. phase = (b>>3)&7: r12's (b&15) gave blocks on one XCD only 2 distinct
//     window positions (b = x mod 8 -> phases x, x+8). Now consecutive
//     blocks ON THE SAME XCD cover consecutive windows.
//  3. Cs aliased onto Ah (Cs only live after the main loop) so the larger
//     staging fits 2 blocks/CU (66.5 KB LDS).
// Everything else identical to r11/r12 (staging pattern, 3-term MFMA,
// epilogue). Numerics: same bf16-split floor (absmax 2^-8 across r6-r12,
// accumulation-order-insensitive).

#define T_TOKENS 32768
#define D_MODEL  1024
#define NE       64
#define NCOL     128
#define M_TILE   64
#define KSTAGE   128
#define NSTAGE   8
#define CS_LD    68
#define OUT_IDX_BASE ((size_t)T_TOKENS * NE)
#define W_ELEMS  (NCOL * D_MODEL)

typedef short  bf16x8  __attribute__((ext_vector_type(8)));
typedef float  floatx4 __attribute__((ext_vector_type(4)));

__device__ __forceinline__ float softplus_f(float x) {
    return fmaxf(x, 0.f) + log1pf(expf(-fabsf(x)));
}

// 8 floats -> packed bf16 hi (int4) + bf16 lo (int4). RNE hi, exact residual,
// RNE lo — numerically identical to rounds 2-12.
__device__ __forceinline__ void cvt8(const float4 a, const float4 b,
                                     int4* hi, int4* lo) {
    float v[8] = {a.x, a.y, a.z, a.w, b.x, b.y, b.z, b.w};
    int hw[4], lw[4];
    #pragma unroll
    for (int p = 0; p < 4; ++p) {
        float2 f2 = make_float2(v[2 * p], v[2 * p + 1]);
        __hip_bfloat162 h2 = __float22bfloat162_rn(f2);
        int u; __builtin_memcpy(&u, &h2, 4);
        float h0 = __uint_as_float(((unsigned)u) << 16);
        float h1 = __uint_as_float(((unsigned)u) & 0xFFFF0000u);
        float2 l2 = make_float2(v[2 * p] - h0, v[2 * p + 1] - h1);
        __hip_bfloat162 L2 = __float22bfloat162_rn(l2);
        int ul; __builtin_memcpy(&ul, &L2, 4);
        hw[p] = u; lw[p] = ul;
    }
    *hi = make_int4(hw[0], hw[1], hw[2], hw[3]);
    *lo = make_int4(lw[0], lw[1], lw[2], lw[3]);
}

// ---------------- prepack: W -> hi/lo bf16 in B-frag order ----------------
// elem index = ((ntile*128 + kgrp)*16 + n16)*8 + j ; value = W[ntile*16+n16][kgrp*8+j]
__global__ __launch_bounds__(256) void prepack_w(
    const float* __restrict__ Wr, const float* __restrict__ Wn,
    short* __restrict__ Bh, short* __restrict__ Bl)
{
    int g   = blockIdx.x * 256 + threadIdx.x;
    int n   = g & 15;
    int kg  = (g >> 4) & 127;
    int t2  = g >> 11;
    int col = t2 * 16 + n;
    const float* src = (col < NE ? Wr + (size_t)col * D_MODEL
                                 : Wn + (size_t)(col - NE) * D_MODEL) + kg * 8;
    float4 a = *(const float4*)src;
    float4 b = *(const float4*)(src + 4);
    int4 hi, lo;
    cvt8(a, b, &hi, &lo);
    *(int4*)(Bh + (size_t)g * 8) = hi;
    *(int4*)(Bl + (size_t)g * 8) = lo;
}

// ---------------- main fused kernel ----------------
__global__ __launch_bounds__(256, 2) void router_mfma(
    const float* __restrict__ A,
    const float* __restrict__ noise,
    const float* __restrict__ br,
    const float* __restrict__ bn,
    const short* __restrict__ Bh,
    const short* __restrict__ Bl,
    float* __restrict__ out)
{
    // frag-order staged A, K=128 per stage (4 MFMA chunks), double-buffered.
    // Ah/Al = 32 KB each. Cs (17.4 KB) aliases Ah: Cs is only live after the
    // main loop's final barrier, when all Ah reads have retired.
    __shared__ __align__(16) short Ah[2][M_TILE * KSTAGE];
    __shared__ __align__(16) short Al[2][M_TILE * KSTAGE];
    __shared__ float s_p1[M_TILE], s_p2[M_TILE];
    __shared__ int   s_e1[M_TILE], s_e2[M_TILE];
    float* Cs = reinterpret_cast<float*>(&Ah[0][0]);   // alias, post-loop only

    const int tid  = threadIdx.x;
    const int lane = tid & 63;
    const int wid  = tid >> 6;   // wave: route ntile wid, noise ntile wid+4
    const int n16  = lane & 15;
    const int quad = lane >> 4;
    const int m0   = blockIdx.x * M_TILE;

    // per-block K-phase: (b>>3) so blocks on the SAME XCD (b = x mod 8) get
    // consecutive phases -> full window coverage per-XCD and chip-wide.
    const int phase = (blockIdx.x >> 3) & (NSTAGE - 1);

    // staging: row r = tid&63, kgrp g = tid>>6; thread stages 32 floats/stage
    // (4 chunks x 8 floats), frag-order dest ((c*4+g)*64 + r)*8 -> 16B
    // aligned, conflict-free (r6/r11 measured SQ_LDS_BANK_CONFLICT == 0).
    const int r  = tid & 63;
    const int g  = tid >> 6;
    const float* pA = A + (size_t)(m0 + r) * D_MODEL + g * 8;
    const int sBase = (g * M_TILE + r) * 8;    // chunk c dest = sBase + c*2048

    const short* pBhR = Bh + ((size_t)(wid * 128 + quad) * 16 + n16) * 8;
    const short* pBlR = Bl + ((size_t)(wid * 128 + quad) * 16 + n16) * 8;
    const short* pBhN = Bh + ((size_t)((4 + wid) * 128 + quad) * 16 + n16) * 8;
    const short* pBlN = Bl + ((size_t)((4 + wid) * 128 + quad) * 16 + n16) * 8;

    floatx4 acc[4][2];   // [m-frag][route/noise]
    #pragma unroll
    for (int i = 0; i < 4; ++i) { acc[i][0] = (floatx4)0.f; acc[i][1] = (floatx4)0.f; }

    // ---- prologue: stage window w0 into buf 0; raw A for w1; B chunk0(w0) ----
    const int w0 = phase;
    const int w1 = (phase + 1) & (NSTAGE - 1);
    {
        const float* q = pA + w0 * KSTAGE;
        #pragma unroll
        for (int c = 0; c < 4; ++c) {
            float4 a0 = *(const float4*)(q + c * 32);
            float4 a1 = *(const float4*)(q + c * 32 + 4);
            int4 hi, lo;
            cvt8(a0, a1, &hi, &lo);
            *(int4*)&Ah[0][sBase + c * 2048] = hi;
            *(int4*)&Al[0][sBase + c * 2048] = lo;
        }
    }
    float4 nxa[4], nxb[4];
    {
        const float* q = pA + w1 * KSTAGE;
        #pragma unroll
        for (int c = 0; c < 4; ++c) {
            nxa[c] = *(const float4*)(q + c * 32);
            nxb[c] = *(const float4*)(q + c * 32 + 4);
        }
    }
    bf16x8 c0hR = *(const bf16x8*)(pBhR + (w0 * 4) * 512);
    bf16x8 c0lR = *(const bf16x8*)(pBlR + (w0 * 4) * 512);
    bf16x8 c0hN = *(const bf16x8*)(pBhN + (w0 * 4) * 512);
    bf16x8 c0lN = *(const bf16x8*)(pBlN + (w0 * 4) * 512);
    __syncthreads();

    float nz[4][4];   // noise prefetch (filled at stage NSTAGE-3)

    for (int s = 0; s < NSTAGE; ++s) {
        const int cur = s & 1, nxt = cur ^ 1;
        const int ps  = (s + phase) & (NSTAGE - 1);   // physical K-window

        // raw A for stage s+2 (window (ps+2) mod 8)
        float4 fa[4], fb[4];
        if (s + 2 < NSTAGE) {
            const float* q = pA + ((ps + 2) & (NSTAGE - 1)) * KSTAGE;
            #pragma unroll
            for (int c = 0; c < 4; ++c) {
                fa[c] = *(const float4*)(q + c * 32);
                fb[c] = *(const float4*)(q + c * 32 + 4);
            }
        }

        // B chunks 1..3 of this window; chunk0 of next window
        bf16x8 bh[4][2], bl[4][2];   // [chunk][route/noise]
        bh[0][0] = c0hR; bl[0][0] = c0lR; bh[0][1] = c0hN; bl[0][1] = c0lN;
        #pragma unroll
        for (int c = 1; c < 4; ++c) {
            const int o = (ps * 4 + c) * 512;
            bh[c][0] = *(const bf16x8*)(pBhR + o);
            bl[c][0] = *(const bf16x8*)(pBlR + o);
            bh[c][1] = *(const bf16x8*)(pBhN + o);
            bl[c][1] = *(const bf16x8*)(pBlN + o);
        }
        bf16x8 n0hR, n0lR, n0hN, n0lN;
        if (s + 1 < NSTAGE) {
            const int o = (((ps + 1) & (NSTAGE - 1)) * 4) * 512;
            n0hR = *(const bf16x8*)(pBhR + o);
            n0lR = *(const bf16x8*)(pBlR + o);
            n0hN = *(const bf16x8*)(pBhN + o);
            n0lN = *(const bf16x8*)(pBlN + o);
        }

        // noise prefetch: 16 scalar loads, ~2 stages before use
        if (s == NSTAGE - 3) {
            const int e = wid * 16 + n16;
            #pragma unroll
            for (int mf = 0; mf < 4; ++mf)
                #pragma unroll
                for (int rr = 0; rr < 4; ++rr)
                    nz[mf][rr] = noise[(size_t)(m0 + mf * 16 + quad * 4 + rr) * NE + e];
        }

        // ---- 4 chunks x (4 m-frags x 6 MFMAs) ----
        #pragma unroll
        for (int c = 0; c < 4; ++c) {
            #pragma unroll
            for (int mf = 0; mf < 4; ++mf) {
                const int gi = ((c * 4 + quad) * M_TILE + mf * 16 + n16) * 8;
                bf16x8 afh = *(const bf16x8*)&Ah[cur][gi];
                bf16x8 afl = *(const bf16x8*)&Al[cur][gi];
                acc[mf][0] = __builtin_amdgcn_mfma_f32_16x16x32_bf16(afh, bh[c][0], acc[mf][0], 0, 0, 0);
                acc[mf][0] = __builtin_amdgcn_mfma_f32_16x16x32_bf16(afh, bl[c][0], acc[mf][0], 0, 0, 0);
                acc[mf][0] = __builtin_amdgcn_mfma_f32_16x16x32_bf16(afl, bh[c][0], acc[mf][0], 0, 0, 0);
                acc[mf][1] = __builtin_amdgcn_mfma_f32_16x16x32_bf16(afh, bh[c][1], acc[mf][1], 0, 0, 0);
                acc[mf][1] = __builtin_amdgcn_mfma_f32_16x16x32_bf16(afh, bl[c][1], acc[mf][1], 0, 0, 0);
                acc[mf][1] = __builtin_amdgcn_mfma_f32_16x16x32_bf16(afl, bh[c][1], acc[mf][1], 0, 0, 0);
            }
        }

        // stage s+1 (raw regs loaded last iteration)
        if (s + 1 < NSTAGE) {
            #pragma unroll
            for (int c = 0; c < 4; ++c) {
                int4 hi, lo;
                cvt8(nxa[c], nxb[c], &hi, &lo);
                *(int4*)&Ah[nxt][sBase + c * 2048] = hi;
                *(int4*)&Al[nxt][sBase + c * 2048] = lo;
            }
        }

        __syncthreads();

        #pragma unroll
        for (int c = 0; c < 4; ++c) { nxa[c] = fa[c]; nxb[c] = fb[c]; }
        c0hR = n0hR; c0lR = n0lR; c0hN = n0hN; c0lN = n0lN;
    }

    // ---- lane-local fuse: noisy = route + noise * softplus(noise_logit) ----
    // Cs aliases Ah — all Ah reads retired before the loop's final barrier.
    {
        const int e = wid * 16 + n16;
        float brv = br[e], bnv = bn[e];
        #pragma unroll
        for (int mf = 0; mf < 4; ++mf)
            #pragma unroll
            for (int rr = 0; rr < 4; ++rr) {
                int t = mf * 16 + quad * 4 + rr;
                float route = acc[mf][0][rr] + brv;
                float nl    = acc[mf][1][rr] + bnv;
                Cs[t * CS_LD + e] = fmaf(nz[mf][rr], softplus_f(nl), route);
            }
    }
    __syncthreads();

    // ---- top-2 + softmax: 4 waves x 16 tokens (in-order scan = stable ties)
    if (lane < 16) {
        const int t = wid * 16 + lane;
        float v1 = -INFINITY, v2 = -INFINITY;
        int e1 = 0, e2 = 0;
        #pragma unroll
        for (int e4 = 0; e4 < 16; ++e4) {
            float4 q = *(const float4*)&Cs[t * CS_LD + e4 * 4];
            float qa[4] = {q.x, q.y, q.z, q.w};
            #pragma unroll
            for (int c = 0; c < 4; ++c) {
                float v = qa[c];
                int e = e4 * 4 + c;
                if (v > v1) { v2 = v1; e2 = e1; v1 = v; e1 = e; }
                else if (v > v2) { v2 = v; e2 = e; }
            }
        }
        float ex = expf(v2 - v1);
        float denom = 1.f + ex;
        s_p1[t] = 1.f / denom;
        s_p2[t] = ex / denom;
        s_e1[t] = e1;
        s_e2[t] = e2;
        float2 iv = make_float2((float)e1, (float)e2);
        *(float2*)(out + OUT_IDX_BASE + (size_t)(m0 + t) * 2) = iv;
    }
    __syncthreads();

    // ---- coalesced scatter of router_output [64 tokens x 64 experts] ----
    #pragma unroll
    for (int i = 0; i < 4; ++i) {
        int gi = i * 256 + tid;       // 0..1023 float4s
        int t  = gi >> 4;
        int e0 = (gi & 15) * 4;
        float p1 = s_p1[t], p2 = s_p2[t];
        int   e1 = s_e1[t], e2 = s_e2[t];
        float4 v;
        v.x = (e0 + 0 == e1) ? p1 : ((e0 + 0 == e2) ? p2 : 0.f);
        v.y = (e0 + 1 == e1) ? p1 : ((e0 + 1 == e2) ? p2 : 0.f);
        v.z = (e0 + 2 == e1) ? p1 : ((e0 + 2 == e2) ? p2 : 0.f);
        v.w = (e0 + 3 == e1) ? p1 : ((e0 + 3 == e2) ? p2 : 0.f);
        *(float4*)(out + (size_t)(m0 + t) * NE + e0) = v;
    }
}

extern "C" void kernel_launch(void* const* d_in, const int* in_sizes, int n_in,
                              void* d_out, int out_size, void* d_ws, size_t ws_size,
                              hipStream_t stream) {
    const float* A     = (const float*)d_in[0];
    const float* noise = (const float*)d_in[1];
    const float* Wr    = (const float*)d_in[2];
    const float* br    = (const float*)d_in[3];
    const float* Wn    = (const float*)d_in[4];
    const float* bn    = (const float*)d_in[5];
    float* out = (float*)d_out;

    short* Bh = (short*)d_ws;
    short* Bl = Bh + W_ELEMS;

    prepack_w<<<dim3(W_ELEMS / 8 / 256), dim3(256), 0, stream>>>(Wr, Wn, Bh, Bl);
    router_mfma<<<dim3(T_TOKENS / M_TILE), dim3(256), 0, stream>>>(A, noise, br, bn, Bh, Bl, out);
}